// Round 8
// baseline (192.346 us; speedup 1.0000x reference)
//
#include <hip/hip_runtime.h>

#define BATCH   1048576
#define IN_DIM  64
#define OUT_DIM 16

// ---------------------------------------------------------------------------
// Kernel 1: build At = A^T (64x16) -> ws[0:1024) and Ct = (G*A)^T (64x16)
// -> ws[1024:2048), where G = (A A^T)^-1. Gauss-Jordan w/ partial pivoting.
// Single block, 256 threads. (validated rounds 1-7)
// ---------------------------------------------------------------------------
__global__ __launch_bounds__(256) void precompute_kernel(
    const float* __restrict__ A, float* __restrict__ ws)
{
    __shared__ float sA[16][64];
    __shared__ float M[16][32];   // [S | I]
    __shared__ float fac[16];
    __shared__ int piv;

    const int tid = threadIdx.x;

    for (int i = tid; i < 1024; i += 256) sA[i >> 6][i & 63] = A[i];
    __syncthreads();

    {
        const int i = tid >> 4, j = tid & 15;
        float s = 0.f;
        #pragma unroll
        for (int k = 0; k < 64; ++k) s = fmaf(sA[i][k], sA[j][k], s);
        M[i][j] = s;
        M[i][16 + j] = (i == j) ? 1.f : 0.f;
    }
    __syncthreads();

    for (int p = 0; p < 16; ++p) {
        if (tid == 0) {
            int best = p;
            float bv = fabsf(M[p][p]);
            for (int r = p + 1; r < 16; ++r) {
                float v = fabsf(M[r][p]);
                if (v > bv) { bv = v; best = r; }
            }
            piv = best;
        }
        __syncthreads();
        if (tid < 32) {
            const int pr = piv;
            if (pr != p) { float t = M[p][tid]; M[p][tid] = M[pr][tid]; M[pr][tid] = t; }
        }
        __syncthreads();
        const float pv = M[p][p];
        __syncthreads();
        if (tid < 32) M[p][tid] *= (1.0f / pv);
        __syncthreads();
        if (tid < 16) fac[tid] = M[tid][p];
        __syncthreads();
        for (int e = tid; e < 512; e += 256) {
            const int r = e >> 5, c = e & 31;
            if (r != p) M[r][c] = fmaf(-fac[r], M[p][c], M[r][c]);
        }
        __syncthreads();
    }

    // At[k*16 + j] = A[j][k]
    for (int e = tid; e < 1024; e += 256) {
        const int k = e >> 4, j = e & 15;
        ws[e] = sA[j][k];
    }
    // Ct[k*16 + i] = C[i][k] = sum_j G[i][j] * A[j][k]
    for (int e = tid; e < 1024; e += 256) {
        const int k = e >> 4, i = e & 15;
        float s = 0.f;
        #pragma unroll
        for (int j = 0; j < 16; ++j) s = fmaf(M[i][16 + j], sA[j][k], s);
        ws[1024 + e] = s;
    }
}

// ---------------------------------------------------------------------------
// Kernel 2: x = y - C^T (A y - b), thread-per-row, k-HALF ping-pong through
// an 8 KB/wave LDS buffer (32 KB/block -> 5 blocks/CU -> 20 waves/CU, vs
// round-7's 64 KB -> 2 waves/SIMD latency trap). Half-tile global access =
// 8 insts x 8 full 128B lines (line-perfect). Phase 2 does the LDS-resident
// k-half first; the other half re-reads y from global (L2/L3 2nd touch).
// Matrices ride the SMEM/K$ path; swizzle slot^(row&7) keeps LDS at the
// uniform b128 floor. Wave-private buffer -> no barriers.
// ---------------------------------------------------------------------------
__global__ __launch_bounds__(256, 5) void apply_kernel(
    const float* __restrict__ y, const float* __restrict__ b,
    const float* __restrict__ ws, float* __restrict__ out)
{
    __shared__ float4 buf[4][64][8];   // 32 KB: 8 KB per wave

    const int tid = threadIdx.x;
    const int wv  = tid >> 6;
    const int l   = tid & 63;
    const size_t wbase = (size_t)blockIdx.x * 256 + (size_t)wv * 64;

    const float4* __restrict__ At4 = reinterpret_cast<const float4*>(ws);        // At[k][j] : k*4+jq
    const float4* __restrict__ Ct4 = reinterpret_cast<const float4*>(ws + 1024); // Ct[k][i] : k*4+iq
    const float*  __restrict__ yb  = y   + wbase * 64;
    float*        __restrict__ ob  = out + wbase * 64;
    const float4* __restrict__ b4  = reinterpret_cast<const float4*>(b) + (wbase + l) * 4;

    const int srow = l >> 3;   // staging row-in-group 0..7
    const int ssl  = l & 7;    // staging 16B slot 0..7

    float t[16];

    // ---- stage half-0 (k=0:32): 8 loads, each 8 full 128B lines ----
    {
        float4 st[8];
        #pragma unroll
        for (int i = 0; i < 8; ++i) {
            const int row = i * 8 + srow;
            st[i] = *reinterpret_cast<const float4*>(yb + row * 64 + ssl * 4);
        }
        #pragma unroll
        for (int q = 0; q < 4; ++q) {
            const float4 bv = b4[q];
            t[4*q+0] = -bv.x; t[4*q+1] = -bv.y; t[4*q+2] = -bv.z; t[4*q+3] = -bv.w;
        }
        #pragma unroll
        for (int i = 0; i < 8; ++i) {
            const int row = i * 8 + srow;
            buf[wv][row][ssl ^ (row & 7)] = st[i];
        }
    }

    // ---- phase 1a: t += A[:,0:32] . y[0:32] ----
    #pragma unroll
    for (int q = 0; q < 8; ++q) {
        const float4 yv = buf[wv][l][q ^ (l & 7)];
        #pragma unroll
        for (int dk = 0; dk < 4; ++dk) {
            const float yk = (dk == 0) ? yv.x : (dk == 1) ? yv.y :
                             (dk == 2) ? yv.z : yv.w;
            const int k = q * 4 + dk;
            #pragma unroll
            for (int jq = 0; jq < 4; ++jq) {
                const float4 a = At4[k * 4 + jq];
                t[4*jq+0] = fmaf(a.x, yk, t[4*jq+0]);
                t[4*jq+1] = fmaf(a.y, yk, t[4*jq+1]);
                t[4*jq+2] = fmaf(a.z, yk, t[4*jq+2]);
                t[4*jq+3] = fmaf(a.w, yk, t[4*jq+3]);
            }
        }
    }

    // ---- stage half-1 (k=32:64) into same buffer ----
    {
        float4 st[8];
        #pragma unroll
        for (int i = 0; i < 8; ++i) {
            const int row = i * 8 + srow;
            st[i] = *reinterpret_cast<const float4*>(yb + row * 64 + 32 + ssl * 4);
        }
        #pragma unroll
        for (int i = 0; i < 8; ++i) {
            const int row = i * 8 + srow;
            buf[wv][row][ssl ^ (row & 7)] = st[i];
        }
    }

    // ---- phase 1b: t += A[:,32:64] . y[32:64]  -> t complete ----
    #pragma unroll
    for (int q = 0; q < 8; ++q) {
        const float4 yv = buf[wv][l][q ^ (l & 7)];
        #pragma unroll
        for (int dk = 0; dk < 4; ++dk) {
            const float yk = (dk == 0) ? yv.x : (dk == 1) ? yv.y :
                             (dk == 2) ? yv.z : yv.w;
            const int k = 32 + q * 4 + dk;
            #pragma unroll
            for (int jq = 0; jq < 4; ++jq) {
                const float4 a = At4[k * 4 + jq];
                t[4*jq+0] = fmaf(a.x, yk, t[4*jq+0]);
                t[4*jq+1] = fmaf(a.y, yk, t[4*jq+1]);
                t[4*jq+2] = fmaf(a.z, yk, t[4*jq+2]);
                t[4*jq+3] = fmaf(a.w, yk, t[4*jq+3]);
            }
        }
    }

    // ---- phase 2b: x[32:64] = y[32:64] - Ct[32:64] t (y still in LDS) ----
    #pragma unroll
    for (int q = 0; q < 8; ++q) {
        const float4 yv = buf[wv][l][q ^ (l & 7)];
        float xv[4];
        #pragma unroll
        for (int dk = 0; dk < 4; ++dk) {
            const int k = 32 + q * 4 + dk;
            float x = (dk == 0) ? yv.x : (dk == 1) ? yv.y :
                      (dk == 2) ? yv.z : yv.w;
            #pragma unroll
            for (int iq = 0; iq < 4; ++iq) {
                const float4 c = Ct4[k * 4 + iq];
                x = fmaf(-c.x, t[4*iq+0], x);
                x = fmaf(-c.y, t[4*iq+1], x);
                x = fmaf(-c.z, t[4*iq+2], x);
                x = fmaf(-c.w, t[4*iq+3], x);
            }
            xv[dk] = x;
        }
        buf[wv][l][q ^ (l & 7)] = make_float4(xv[0], xv[1], xv[2], xv[3]);
    }

    // ---- store half-1 ----
    #pragma unroll
    for (int i = 0; i < 8; ++i) {
        const int row = i * 8 + srow;
        *reinterpret_cast<float4*>(ob + row * 64 + 32 + ssl * 4) =
            buf[wv][row][ssl ^ (row & 7)];
    }

    // ---- phase 2a: x[0:32] = y[0:32] - Ct[0:32] t (y re-read from global,
    //      2nd touch -> L2/L3; x written to freed buffer for coalesced store)
    #pragma unroll
    for (int q = 0; q < 8; ++q) {
        const float4 yv = *reinterpret_cast<const float4*>(yb + l * 64 + q * 4);
        float xv[4];
        #pragma unroll
        for (int dk = 0; dk < 4; ++dk) {
            const int k = q * 4 + dk;
            float x = (dk == 0) ? yv.x : (dk == 1) ? yv.y :
                      (dk == 2) ? yv.z : yv.w;
            #pragma unroll
            for (int iq = 0; iq < 4; ++iq) {
                const float4 c = Ct4[k * 4 + iq];
                x = fmaf(-c.x, t[4*iq+0], x);
                x = fmaf(-c.y, t[4*iq+1], x);
                x = fmaf(-c.z, t[4*iq+2], x);
                x = fmaf(-c.w, t[4*iq+3], x);
            }
            xv[dk] = x;
        }
        buf[wv][l][q ^ (l & 7)] = make_float4(xv[0], xv[1], xv[2], xv[3]);
    }

    // ---- store half-0 ----
    #pragma unroll
    for (int i = 0; i < 8; ++i) {
        const int row = i * 8 + srow;
        *reinterpret_cast<float4*>(ob + row * 64 + ssl * 4) =
            buf[wv][row][ssl ^ (row & 7)];
    }
}

// ---------------------------------------------------------------------------
extern "C" void kernel_launch(void* const* d_in, const int* in_sizes, int n_in,
                              void* d_out, int out_size, void* d_ws, size_t ws_size,
                              hipStream_t stream) {
    const float* y = (const float*)d_in[0];   // (1048576, 64)
    const float* A = (const float*)d_in[1];   // (16, 64)
    const float* b = (const float*)d_in[2];   // (1048576, 16)
    float* out = (float*)d_out;               // (1048576, 64)
    float* ws  = (float*)d_ws;                // 2048 floats: At(1024) + Ct(1024)

    precompute_kernel<<<1, 256, 0, stream>>>(A, ws);
    apply_kernel<<<BATCH / 256, 256, 0, stream>>>(y, b, ws, out);
}